// Round 6
// baseline (1113.369 us; speedup 1.0000x reference)
//
#include <hip/hip_runtime.h>

#define DD 64

__device__ __forceinline__ float fast_tanh(float x) {
    float e = __builtin_amdgcn_exp2f(x * 2.885390081777927f); // 2x * log2(e)
    return 1.0f - 2.0f * __builtin_amdgcn_rcpf(e + 1.0f);
}

// ---------------- CSR build ----------------

__global__ void __launch_bounds__(256) count_deg(
    const int* __restrict__ dst, int* __restrict__ deg, int E)
{
    int e = blockIdx.x * 256 + threadIdx.x;
    if (e < E) atomicAdd(&deg[dst[e]], 1);
}

// single block, 1024 threads: exclusive scan deg[N] -> off[N+1], cursor = off
__global__ void __launch_bounds__(1024) scan_kernel(
    const int* __restrict__ deg, int* __restrict__ off,
    int* __restrict__ cursor, int N)
{
    __shared__ int part[1024];
    int t = threadIdx.x;
    int per = (N + 1023) / 1024;
    int lo = t * per;
    int hi = lo + per; if (hi > N) hi = N;
    int s = 0;
    for (int i = lo; i < hi; ++i) s += deg[i];
    part[t] = s;
    __syncthreads();
    for (int d = 1; d < 1024; d <<= 1) {
        int v = 0;
        if (t >= d) v = part[t - d];
        __syncthreads();
        if (t >= d) part[t] += v;
        __syncthreads();
    }
    int run = (t == 0) ? 0 : part[t - 1];
    for (int i = lo; i < hi; ++i) {
        off[i] = run; cursor[i] = run;
        run += deg[i];
    }
    if (lo < N && hi == N) off[N] = run;
}

__global__ void __launch_bounds__(256) fill_eidx(
    const int* __restrict__ dst, int* __restrict__ cursor,
    int* __restrict__ eidx, int E)
{
    int e = blockIdx.x * 256 + threadIdx.x;
    if (e < E) {
        int slot = atomicAdd(&cursor[dst[e]], 1);
        eidx[slot] = e;
    }
}

// ---------------- compute kernels ----------------
// Rule #20 (scratch): NO runtime-indexed local arrays. All acc[]/load temps
// use compile-time-static indices (full unroll) so they live in VGPRs.
// (256,2): 256-VGPR cap, 2 blocks/CU (= LDS limit for the fused kernel).

// hm = h @ W(top 64x64) + b ; zero pooled (atomics accumulate into it)
__global__ void __launch_bounds__(256, 2) node_transform(
    const float* __restrict__ h, const float* __restrict__ W,
    const float* __restrict__ b, float* __restrict__ hm,
    float* __restrict__ pooled, int N)
{
    int n = blockIdx.x * 256 + threadIdx.x;
    if (n >= N) return;
    float acc[DD];
    #pragma unroll
    for (int j = 0; j < DD; ++j) acc[j] = b[j];
    const float4* hrow = reinterpret_cast<const float4*>(h + (size_t)n * DD);
    #pragma unroll
    for (int kk = 0; kk < DD / 4; ++kk) {
        float4 a = hrow[kk];                 // SSA per iteration -> VGPRs
        const float* Wr = W + kk * 4 * DD;   // uniform -> s_load
        #pragma unroll
        for (int j = 0; j < DD; ++j)
            acc[j] += a.x * Wr[j] + a.y * Wr[DD + j]
                    + a.z * Wr[2 * DD + j] + a.w * Wr[3 * DD + j];
    }
    float4* orow = reinterpret_cast<float4*>(hm + (size_t)n * DD);
    float4* prow = reinterpret_cast<float4*>(pooled + (size_t)n * DD);
    #pragma unroll
    for (int jj = 0; jj < DD / 4; ++jj) {
        orow[jj] = make_float4(acc[4*jj], acc[4*jj+1], acc[4*jj+2], acc[4*jj+3]);
        prow[jj] = make_float4(0.f, 0.f, 0.f, 0.f);
    }
}

// Fused: per CSR slot compute msg = tanh(ef[e]@W + hm[src]); store msg to the
// thread's OWN LDS row (XOR-swizzled, conflict-free, no atomics); then
// segment-sum by READING LDS: wave-per-node, lane = channel.
__global__ void __launch_bounds__(256, 2) fused_edge_gather(
    const float* __restrict__ ef, const float* __restrict__ hm,
    const int* __restrict__ src, const int* __restrict__ dst,
    const int* __restrict__ off, const int* __restrict__ eidx,
    const float* __restrict__ W, float* __restrict__ pooled,
    int E, int N)
{
    __shared__ float tile[256 * DD];   // 64 KiB; float4 slot k stored at k^(row&15)
    int t  = threadIdx.x;
    int s0 = blockIdx.x * 256;
    int s1 = s0 + 256; if (s1 > E) s1 = E;

    // ---- phase 1: per-slot message into own LDS row ----
    int slot = s0 + t;
    if (slot < s1) {
        int e = eidx[slot];
        int s = src[e];
        const float4* erow = reinterpret_cast<const float4*>(ef + (size_t)e * DD);
        const float4* hrow = reinterpret_cast<const float4*>(hm + (size_t)s * DD);
        float acc[DD];
        #pragma unroll
        for (int j = 0; j < DD; ++j) acc[j] = 0.0f;
        #pragma unroll
        for (int kk = 0; kk < 16; ++kk) {
            float4 aa = erow[kk];            // static unroll: SSA -> VGPR,
            const float* Wr = W + kk * 4 * DD;  // scheduler hoists loads
            #pragma unroll
            for (int j = 0; j < DD; ++j)
                acc[j] += aa.x * Wr[j] + aa.y * Wr[DD + j]
                        + aa.z * Wr[2 * DD + j] + aa.w * Wr[3 * DD + j];
        }
        #pragma unroll
        for (int jj = 0; jj < 16; ++jj) {
            float4 hv = hrow[jj];
            float4 m;
            m.x = fast_tanh(acc[4*jj+0] + hv.x);
            m.y = fast_tanh(acc[4*jj+1] + hv.y);
            m.z = fast_tanh(acc[4*jj+2] + hv.z);
            m.w = fast_tanh(acc[4*jj+3] + hv.w);
            int sl = (jj ^ (t & 15)) << 2;       // XOR swizzle: spread quads
            *reinterpret_cast<float4*>(&tile[t * DD + sl]) = m;
        }
    }
    __syncthreads();

    // ---- phase 2: segment-sum from LDS; wave per node, lane = channel ----
    int d_first = dst[eidx[s0]];                 // uniform -> broadcast
    int d_last  = dst[eidx[s1 - 1]];
    int ch = t & 63;
    int c4 = ch >> 2, ce = ch & 3;
    for (int n = d_first + (t >> 6); n <= d_last; n += 4) {
        int lo = off[n], hi = off[n + 1];
        int clo = lo > s0 ? lo : s0;
        int chi = hi < s1 ? hi : s1;
        if (clo >= chi) continue;                // node untouched by this block
        float v = 0.0f;
        for (int s = clo; s < chi; ++s) {
            int r = s - s0;
            v += tile[r * DD + ((c4 ^ (r & 15)) << 2) + ce];
        }
        if (lo >= s0 && hi <= s1)
            pooled[(size_t)n * DD + ch] = v;     // exclusively owned -> store
        else
            atomicAdd(pooled + (size_t)n * DD + ch, v);  // straddles blocks
    }
}

// fallback path: atomic scatter if ws too small
__global__ void __launch_bounds__(256, 2) edge_kernel_atomic(
    const float* __restrict__ ef, const float* __restrict__ hm,
    const int* __restrict__ src, const int* __restrict__ dst,
    const float* __restrict__ W, float* __restrict__ pooled, int E)
{
    int e = blockIdx.x * 256 + threadIdx.x;
    if (e >= E) return;
    int s = src[e];
    int d = dst[e];
    float acc[DD];
    #pragma unroll
    for (int j = 0; j < DD; ++j) acc[j] = 0.0f;
    const float4* erow = reinterpret_cast<const float4*>(ef + (size_t)e * DD);
    #pragma unroll
    for (int kk = 0; kk < DD / 4; ++kk) {
        float4 a = erow[kk];
        const float* Wr = W + kk * 4 * DD;
        #pragma unroll
        for (int j = 0; j < DD; ++j)
            acc[j] += a.x * Wr[j] + a.y * Wr[DD + j]
                    + a.z * Wr[2 * DD + j] + a.w * Wr[3 * DD + j];
    }
    const float4* hrow = reinterpret_cast<const float4*>(hm + (size_t)s * DD);
    float* prow = pooled + (size_t)d * DD;
    #pragma unroll
    for (int jj = 0; jj < DD / 4; ++jj) {
        float4 hv = hrow[jj];
        atomicAdd(prow + 4*jj + 0, fast_tanh(acc[4*jj+0] + hv.x));
        atomicAdd(prow + 4*jj + 1, fast_tanh(acc[4*jj+1] + hv.y));
        atomicAdd(prow + 4*jj + 2, fast_tanh(acc[4*jj+2] + hv.z));
        atomicAdd(prow + 4*jj + 3, fast_tanh(acc[4*jj+3] + hv.w));
    }
}

// h_new = tanh(h @ Wu[0:64] + pooled @ Wu[64:128] + bu)
__global__ void __launch_bounds__(256, 2) update_kernel(
    const float* __restrict__ h, const float* __restrict__ pooled,
    const float* __restrict__ Wu, const float* __restrict__ bu,
    float* __restrict__ hout, int N)
{
    int n = blockIdx.x * 256 + threadIdx.x;
    if (n >= N) return;
    float acc[DD];
    #pragma unroll
    for (int j = 0; j < DD; ++j) acc[j] = bu[j];
    const float4* hrow = reinterpret_cast<const float4*>(h + (size_t)n * DD);
    #pragma unroll
    for (int kk = 0; kk < DD / 4; ++kk) {
        float4 a = hrow[kk];
        const float* Wr = Wu + kk * 4 * DD;
        #pragma unroll
        for (int j = 0; j < DD; ++j)
            acc[j] += a.x * Wr[j] + a.y * Wr[DD + j]
                    + a.z * Wr[2 * DD + j] + a.w * Wr[3 * DD + j];
    }
    const float4* prow = reinterpret_cast<const float4*>(pooled + (size_t)n * DD);
    #pragma unroll
    for (int kk = 0; kk < DD / 4; ++kk) {
        float4 a = prow[kk];
        const float* Wr = Wu + (DD + kk * 4) * DD;
        #pragma unroll
        for (int j = 0; j < DD; ++j)
            acc[j] += a.x * Wr[j] + a.y * Wr[DD + j]
                    + a.z * Wr[2 * DD + j] + a.w * Wr[3 * DD + j];
    }
    float4* orow = reinterpret_cast<float4*>(hout + (size_t)n * DD);
    #pragma unroll
    for (int jj = 0; jj < DD / 4; ++jj)
        orow[jj] = make_float4(fast_tanh(acc[4*jj]),   fast_tanh(acc[4*jj+1]),
                               fast_tanh(acc[4*jj+2]), fast_tanh(acc[4*jj+3]));
}

__global__ void __launch_bounds__(256) out_kernel(
    const float* __restrict__ h, const float* __restrict__ Wo,
    const float* __restrict__ bo, float* __restrict__ out, int N)
{
    int n = blockIdx.x * 256 + threadIdx.x;
    if (n >= N) return;
    const float4* hrow = reinterpret_cast<const float4*>(h + (size_t)n * DD);
    float acc = bo[0];
    #pragma unroll
    for (int kk = 0; kk < DD / 4; ++kk) {
        float4 a = hrow[kk];
        acc += a.x * Wo[4*kk] + a.y * Wo[4*kk+1] + a.z * Wo[4*kk+2] + a.w * Wo[4*kk+3];
    }
    out[n] = acc;
}

extern "C" void kernel_launch(void* const* d_in, const int* in_sizes, int n_in,
                              void* d_out, int out_size, void* d_ws, size_t ws_size,
                              hipStream_t stream) {
    const float* node = (const float*)d_in[0];
    const float* ef   = (const float*)d_in[1];
    const int*   src  = (const int*)d_in[2];
    const int*   dst  = (const int*)d_in[3];
    const float* Wm1  = (const float*)d_in[4];
    const float* bm1  = (const float*)d_in[5];
    const float* Wu1  = (const float*)d_in[6];
    const float* bu1  = (const float*)d_in[7];
    const float* Wm2  = (const float*)d_in[8];
    const float* bm2  = (const float*)d_in[9];
    const float* Wu2  = (const float*)d_in[10];
    const float* bu2  = (const float*)d_in[11];
    const float* Wo   = (const float*)d_in[12];
    const float* bo   = (const float*)d_in[13];
    float* out = (float*)d_out;

    const int N = in_sizes[0] / DD;
    const int E = in_sizes[2];

    // ws layout
    char* p = (char*)d_ws;
    float* h1     = (float*)p; p += (size_t)N * DD * 4;
    float* h2     = (float*)p; p += (size_t)N * DD * 4;
    float* hm     = (float*)p; p += (size_t)N * DD * 4;
    float* pooled = (float*)p; p += (size_t)N * DD * 4;
    int*   deg    = (int*)p;   p += (size_t)N * 4;
    int*   off    = (int*)p;   p += (size_t)(N + 1) * 4;
    int*   cursor = (int*)p;   p += (size_t)N * 4;
    int*   eidx   = (int*)p;   p += (size_t)E * 4;
    size_t needed = (size_t)(p - (char*)d_ws);

    dim3 blk(256);
    int nbN = (N + 255) / 256;
    int nbE = (E + 255) / 256;

    if (ws_size >= needed) {
        // ---- CSR build (stateless: rebuilt every call) ----
        hipMemsetAsync(deg, 0, (size_t)N * 4, stream);
        count_deg<<<nbE, blk, 0, stream>>>(dst, deg, E);
        scan_kernel<<<1, 1024, 0, stream>>>(deg, off, cursor, N);
        fill_eidx<<<nbE, blk, 0, stream>>>(dst, cursor, eidx, E);

        // ---- layer 1 ----
        node_transform<<<nbN, blk, 0, stream>>>(node, Wm1, bm1, hm, pooled, N);
        fused_edge_gather<<<nbE, blk, 0, stream>>>(ef, hm, src, dst, off, eidx,
                                                   Wm1 + DD * DD, pooled, E, N);
        update_kernel<<<nbN, blk, 0, stream>>>(node, pooled, Wu1, bu1, h1, N);

        // ---- layer 2 ----
        node_transform<<<nbN, blk, 0, stream>>>(h1, Wm2, bm2, hm, pooled, N);
        fused_edge_gather<<<nbE, blk, 0, stream>>>(ef, hm, src, dst, off, eidx,
                                                   Wm2 + DD * DD, pooled, E, N);
        update_kernel<<<nbN, blk, 0, stream>>>(h1, pooled, Wu2, bu2, h2, N);
    } else {
        // ---- fallback: atomic scatter path ----
        node_transform<<<nbN, blk, 0, stream>>>(node, Wm1, bm1, hm, pooled, N);
        edge_kernel_atomic<<<nbE, blk, 0, stream>>>(ef, hm, src, dst, Wm1 + DD * DD, pooled, E);
        update_kernel<<<nbN, blk, 0, stream>>>(node, pooled, Wu1, bu1, h1, N);

        node_transform<<<nbN, blk, 0, stream>>>(h1, Wm2, bm2, hm, pooled, N);
        edge_kernel_atomic<<<nbE, blk, 0, stream>>>(ef, hm, src, dst, Wm2 + DD * DD, pooled, E);
        update_kernel<<<nbN, blk, 0, stream>>>(h1, pooled, Wu2, bu2, h2, N);
    }

    // ---- readout ----
    out_kernel<<<nbN, blk, 0, stream>>>(h2, Wo, bo, out, N);
}

// Round 7
// 720.232 us; speedup vs baseline: 1.5458x; 1.5458x over previous
//
#include <hip/hip_runtime.h>

#define DD 64

typedef __attribute__((ext_vector_type(8))) short bf16x8;
typedef __attribute__((ext_vector_type(4))) float f32x4;

__device__ __forceinline__ float fast_tanh(float x) {
    float e = __builtin_amdgcn_exp2f(x * 2.885390081777927f); // 2x * log2(e)
    return 1.0f - 2.0f * __builtin_amdgcn_rcpf(e + 1.0f);
}

__device__ __forceinline__ unsigned f2bf(float f) {
    union { float f; unsigned u; } v; v.f = f;
    return (v.u + 0x7FFFu + ((v.u >> 16) & 1u)) >> 16;   // RNE
}

// ---------------- CSR build ----------------

__global__ void __launch_bounds__(256) count_deg(
    const int* __restrict__ dst, int* __restrict__ deg, int E)
{
    int e = blockIdx.x * 256 + threadIdx.x;
    if (e < E) atomicAdd(&deg[dst[e]], 1);
}

__global__ void __launch_bounds__(1024) scan_kernel(
    const int* __restrict__ deg, int* __restrict__ off,
    int* __restrict__ cursor, int N)
{
    __shared__ int part[1024];
    int t = threadIdx.x;
    int per = (N + 1023) / 1024;
    int lo = t * per;
    int hi = lo + per; if (hi > N) hi = N;
    int s = 0;
    for (int i = lo; i < hi; ++i) s += deg[i];
    part[t] = s;
    __syncthreads();
    for (int d = 1; d < 1024; d <<= 1) {
        int v = 0;
        if (t >= d) v = part[t - d];
        __syncthreads();
        if (t >= d) part[t] += v;
        __syncthreads();
    }
    int run = (t == 0) ? 0 : part[t - 1];
    for (int i = lo; i < hi; ++i) {
        off[i] = run; cursor[i] = run;
        run += deg[i];
    }
    if (lo < N && hi == N) off[N] = run;
}

__global__ void __launch_bounds__(256) fill_eidx(
    const int* __restrict__ dst, int* __restrict__ cursor,
    int* __restrict__ eidx, int E)
{
    int e = blockIdx.x * 256 + threadIdx.x;
    if (e < E) {
        int slot = atomicAdd(&cursor[dst[e]], 1);
        eidx[slot] = e;
    }
}

// wt[n*64+k] = bf16(Wm[(64+k)*64 + n])  -- transposed bottom half of Wm
__global__ void __launch_bounds__(256) prep_wt(
    const float* __restrict__ Wm1, const float* __restrict__ Wm2,
    unsigned short* __restrict__ wt1, unsigned short* __restrict__ wt2)
{
    int i = blockIdx.x * 256 + threadIdx.x;
    if (i < 4096) {
        int n = i >> 6, k = i & 63;
        wt1[i] = (unsigned short)f2bf(Wm1[(64 + k) * 64 + n]);
    } else if (i < 8192) {
        int j = i - 4096;
        int n = j >> 6, k = j & 63;
        wt2[j] = (unsigned short)f2bf(Wm2[(64 + k) * 64 + n]);
    }
}

// ---------------- node-side kernels (fp32, unchanged) ----------------

__global__ void __launch_bounds__(256, 2) node_transform(
    const float* __restrict__ h, const float* __restrict__ W,
    const float* __restrict__ b, float* __restrict__ hm,
    float* __restrict__ pooled, int N)
{
    int n = blockIdx.x * 256 + threadIdx.x;
    if (n >= N) return;
    float acc[DD];
    #pragma unroll
    for (int j = 0; j < DD; ++j) acc[j] = b[j];
    const float4* hrow = reinterpret_cast<const float4*>(h + (size_t)n * DD);
    #pragma unroll
    for (int kk = 0; kk < DD / 4; ++kk) {
        float4 a = hrow[kk];
        const float* Wr = W + kk * 4 * DD;
        #pragma unroll
        for (int j = 0; j < DD; ++j)
            acc[j] += a.x * Wr[j] + a.y * Wr[DD + j]
                    + a.z * Wr[2 * DD + j] + a.w * Wr[3 * DD + j];
    }
    float4* orow = reinterpret_cast<float4*>(hm + (size_t)n * DD);
    float4* prow = reinterpret_cast<float4*>(pooled + (size_t)n * DD);
    #pragma unroll
    for (int jj = 0; jj < DD / 4; ++jj) {
        orow[jj] = make_float4(acc[4*jj], acc[4*jj+1], acc[4*jj+2], acc[4*jj+3]);
        prow[jj] = make_float4(0.f, 0.f, 0.f, 0.f);
    }
}

// ---------------- MFMA fused edge kernel ----------------
// Block = 256 CSR slots, processed as 2 chunks of 128.
// Chunk: stage gathered ef rows as bf16 into swizzled LDS (layer1: convert
// from fp32 and persist CSR-ordered efb; layer2: read efb), MFMA [128x64] =
// A[128x64]@Wt, epilogue adds fp32 hm[src] + tanh -> padded LDS msg tile,
// then segment-sum (wave-per-node, lane=channel) into pooled.
__global__ void __launch_bounds__(256, 2) fused_edge_gather(
    const float* __restrict__ ef, unsigned short* __restrict__ efb,
    const float* __restrict__ hm,
    const int* __restrict__ src, const int* __restrict__ dst,
    const int* __restrict__ off, const int* __restrict__ eidx,
    const unsigned short* __restrict__ wtb, float* __restrict__ pooled,
    int E, int N, int layer1)
{
    __shared__ unsigned short ldsW[64 * 64];   // Wt bf16, swizzled   (8 KB)
    __shared__ unsigned short ldsA[128 * 64];  // ef bf16, swizzled  (16 KB)
    __shared__ float ldsM[128 * 66];           // msg fp32, padded (33.8 KB)
    __shared__ int   ldsSrc[128];

    const int t  = threadIdx.x;
    const int s0 = blockIdx.x * 256;
    const int wv = t >> 6, l = t & 63;
    const int lrow = l & 15, lk = l >> 4;

    // ---- stage Wt (once): thread t -> row n=t>>2, 2 chunks of 8 bf16 ----
    {
        int n = t >> 2, c0 = (t & 3) * 2;
        const uint4* wb = reinterpret_cast<const uint4*>(wtb + n * 64);
        #pragma unroll
        for (int i = 0; i < 2; ++i) {
            int cc = c0 + i;
            *reinterpret_cast<uint4*>(&ldsW[(n * 8 + (cc ^ (n & 7))) * 8]) = wb[cc];
        }
    }

#define STAGE_A(CK)                                                            \
    {                                                                          \
        int cb = s0 + (CK) * 128;                                              \
        int r = t >> 1, half = t & 1;                                          \
        int slot = cb + r;                                                     \
        if (slot < E) {                                                        \
            int e = eidx[slot];                                                \
            if (half == 0) ldsSrc[r] = src[e];                                 \
            if (layer1) {                                                      \
                const float4* er4 =                                            \
                    reinterpret_cast<const float4*>(ef + (size_t)e * 64) + half * 8; \
                uint4* gout =                                                  \
                    reinterpret_cast<uint4*>(efb + (size_t)slot * 64) + half * 4; \
                _Pragma("unroll")                                              \
                for (int c = 0; c < 4; ++c) {                                  \
                    float4 f0 = er4[c * 2], f1 = er4[c * 2 + 1];               \
                    uint4 chv;                                                 \
                    chv.x = f2bf(f0.x) | (f2bf(f0.y) << 16);                   \
                    chv.y = f2bf(f0.z) | (f2bf(f0.w) << 16);                   \
                    chv.z = f2bf(f1.x) | (f2bf(f1.y) << 16);                   \
                    chv.w = f2bf(f1.z) | (f2bf(f1.w) << 16);                   \
                    int cc = half * 4 + c;                                     \
                    *reinterpret_cast<uint4*>(&ldsA[(r * 8 + (cc ^ (r & 7))) * 8]) = chv; \
                    gout[c] = chv;                                             \
                }                                                              \
            } else {                                                           \
                const uint4* eb4 =                                             \
                    reinterpret_cast<const uint4*>(efb + (size_t)slot * 64) + half * 4; \
                _Pragma("unroll")                                              \
                for (int c = 0; c < 4; ++c) {                                  \
                    uint4 chv = eb4[c];                                        \
                    int cc = half * 4 + c;                                     \
                    *reinterpret_cast<uint4*>(&ldsA[(r * 8 + (cc ^ (r & 7))) * 8]) = chv; \
                }                                                              \
            }                                                                  \
        } else {                                                               \
            if (half == 0) ldsSrc[r] = 0;                                      \
            uint4 z = make_uint4(0, 0, 0, 0);                                  \
            _Pragma("unroll")                                                  \
            for (int c = 0; c < 4; ++c) {                                      \
                int cc = half * 4 + c;                                         \
                *reinterpret_cast<uint4*>(&ldsA[(r * 8 + (cc ^ (r & 7))) * 8]) = z; \
            }                                                                  \
        }                                                                      \
    }

#define COMPUTE(CK)                                                            \
    {                                                                          \
        bf16x8 afr[2][2];                                                      \
        _Pragma("unroll")                                                      \
        for (int er = 0; er < 2; ++er) {                                       \
            int row = wv * 32 + er * 16 + lrow;                                \
            _Pragma("unroll")                                                  \
            for (int k2 = 0; k2 < 2; ++k2) {                                   \
                int kc = lk + k2 * 4;                                          \
                afr[er][k2] = *reinterpret_cast<const bf16x8*>(                \
                    &ldsA[(row * 8 + (kc ^ (row & 7))) * 8]);                  \
            }                                                                  \
        }                                                                      \
        f32x4 acc[2][4];                                                       \
        _Pragma("unroll")                                                      \
        for (int er = 0; er < 2; ++er)                                         \
        {                                                                      \
            _Pragma("unroll")                                                  \
            for (int cg = 0; cg < 4; ++cg) {                                   \
                f32x4 z = {0.f, 0.f, 0.f, 0.f};                                \
                acc[er][cg] = __builtin_amdgcn_mfma_f32_16x16x32_bf16(         \
                    afr[er][0], bfr[cg][0], z, 0, 0, 0);                       \
                acc[er][cg] = __builtin_amdgcn_mfma_f32_16x16x32_bf16(         \
                    afr[er][1], bfr[cg][1], acc[er][cg], 0, 0, 0);             \
            }                                                                  \
        }                                                                      \
        _Pragma("unroll")                                                      \
        for (int er = 0; er < 2; ++er) {                                       \
            int rbase = wv * 32 + er * 16 + (lk << 2);                         \
            int sA = ldsSrc[rbase + 0], sB = ldsSrc[rbase + 1];                \
            int sC = ldsSrc[rbase + 2], sD = ldsSrc[rbase + 3];                \
            _Pragma("unroll")                                                  \
            for (int cg = 0; cg < 4; ++cg) {                                   \
                int col = cg * 16 + lrow;                                      \
                float hA = hm[(size_t)sA * 64 + col];                          \
                float hB = hm[(size_t)sB * 64 + col];                          \
                float hC = hm[(size_t)sC * 64 + col];                          \
                float hD = hm[(size_t)sD * 64 + col];                          \
                ldsM[(rbase + 0) * 66 + col] = fast_tanh(acc[er][cg][0] + hA); \
                ldsM[(rbase + 1) * 66 + col] = fast_tanh(acc[er][cg][1] + hB); \
                ldsM[(rbase + 2) * 66 + col] = fast_tanh(acc[er][cg][2] + hC); \
                ldsM[(rbase + 3) * 66 + col] = fast_tanh(acc[er][cg][3] + hD); \
            }                                                                  \
        }                                                                      \
    }

#define PHASE2(CK)                                                             \
    {                                                                          \
        int cb = s0 + (CK) * 128;                                              \
        int ce = cb + 128; if (ce > E) ce = E;                                 \
        if (cb < E) {                                                          \
            int df = dst[eidx[cb]];                                            \
            int dl = dst[eidx[ce - 1]];                                        \
            for (int n = df + wv; n <= dl; n += 4) {                           \
                int lo = off[n], hi = off[n + 1];                              \
                int clo = lo > cb ? lo : cb;                                   \
                int chi = hi < ce ? hi : ce;                                   \
                if (clo >= chi) continue;                                      \
                float v = 0.f;                                                 \
                for (int q = clo; q < chi; ++q) v += ldsM[(q - cb) * 66 + l];  \
                if (lo >= cb && hi <= ce) pooled[(size_t)n * 64 + l] = v;      \
                else atomicAdd(pooled + (size_t)n * 64 + l, v);                \
            }                                                                  \
        }                                                                      \
    }

    STAGE_A(0)
    __syncthreads();

    // B fragments (Wt persistent in LDS, reused for both chunks)
    bf16x8 bfr[4][2];
    #pragma unroll
    for (int cg = 0; cg < 4; ++cg) {
        int n = cg * 16 + lrow;
        #pragma unroll
        for (int k2 = 0; k2 < 2; ++k2) {
            int kc = lk + k2 * 4;
            bfr[cg][k2] = *reinterpret_cast<const bf16x8*>(
                &ldsW[(n * 8 + (kc ^ (n & 7))) * 8]);
        }
    }

    COMPUTE(0)
    __syncthreads();
    STAGE_A(1)       // overwrites ldsA/ldsSrc (chunk0 done with them)
    PHASE2(0)        // reads ldsM chunk0 (disjoint from ldsA)
    __syncthreads();
    COMPUTE(1)
    __syncthreads();
    PHASE2(1)

#undef STAGE_A
#undef COMPUTE
#undef PHASE2
}

// fallback path: atomic scatter if ws too small (fp32 exact)
__global__ void __launch_bounds__(256, 2) edge_kernel_atomic(
    const float* __restrict__ ef, const float* __restrict__ hm,
    const int* __restrict__ src, const int* __restrict__ dst,
    const float* __restrict__ W, float* __restrict__ pooled, int E)
{
    int e = blockIdx.x * 256 + threadIdx.x;
    if (e >= E) return;
    int s = src[e];
    int d = dst[e];
    float acc[DD];
    #pragma unroll
    for (int j = 0; j < DD; ++j) acc[j] = 0.0f;
    const float4* erow = reinterpret_cast<const float4*>(ef + (size_t)e * DD);
    #pragma unroll
    for (int kk = 0; kk < DD / 4; ++kk) {
        float4 a = erow[kk];
        const float* Wr = W + kk * 4 * DD;
        #pragma unroll
        for (int j = 0; j < DD; ++j)
            acc[j] += a.x * Wr[j] + a.y * Wr[DD + j]
                    + a.z * Wr[2 * DD + j] + a.w * Wr[3 * DD + j];
    }
    const float4* hrow = reinterpret_cast<const float4*>(hm + (size_t)s * DD);
    float* prow = pooled + (size_t)d * DD;
    #pragma unroll
    for (int jj = 0; jj < DD / 4; ++jj) {
        float4 hv = hrow[jj];
        atomicAdd(prow + 4*jj + 0, fast_tanh(acc[4*jj+0] + hv.x));
        atomicAdd(prow + 4*jj + 1, fast_tanh(acc[4*jj+1] + hv.y));
        atomicAdd(prow + 4*jj + 2, fast_tanh(acc[4*jj+2] + hv.z));
        atomicAdd(prow + 4*jj + 3, fast_tanh(acc[4*jj+3] + hv.w));
    }
}

// h_new = tanh(h @ Wu[0:64] + pooled @ Wu[64:128] + bu)
__global__ void __launch_bounds__(256, 2) update_kernel(
    const float* __restrict__ h, const float* __restrict__ pooled,
    const float* __restrict__ Wu, const float* __restrict__ bu,
    float* __restrict__ hout, int N)
{
    int n = blockIdx.x * 256 + threadIdx.x;
    if (n >= N) return;
    float acc[DD];
    #pragma unroll
    for (int j = 0; j < DD; ++j) acc[j] = bu[j];
    const float4* hrow = reinterpret_cast<const float4*>(h + (size_t)n * DD);
    #pragma unroll
    for (int kk = 0; kk < DD / 4; ++kk) {
        float4 a = hrow[kk];
        const float* Wr = Wu + kk * 4 * DD;
        #pragma unroll
        for (int j = 0; j < DD; ++j)
            acc[j] += a.x * Wr[j] + a.y * Wr[DD + j]
                    + a.z * Wr[2 * DD + j] + a.w * Wr[3 * DD + j];
    }
    const float4* prow = reinterpret_cast<const float4*>(pooled + (size_t)n * DD);
    #pragma unroll
    for (int kk = 0; kk < DD / 4; ++kk) {
        float4 a = prow[kk];
        const float* Wr = Wu + (DD + kk * 4) * DD;
        #pragma unroll
        for (int j = 0; j < DD; ++j)
            acc[j] += a.x * Wr[j] + a.y * Wr[DD + j]
                    + a.z * Wr[2 * DD + j] + a.w * Wr[3 * DD + j];
    }
    float4* orow = reinterpret_cast<float4*>(hout + (size_t)n * DD);
    #pragma unroll
    for (int jj = 0; jj < DD / 4; ++jj)
        orow[jj] = make_float4(fast_tanh(acc[4*jj]),   fast_tanh(acc[4*jj+1]),
                               fast_tanh(acc[4*jj+2]), fast_tanh(acc[4*jj+3]));
}

__global__ void __launch_bounds__(256) out_kernel(
    const float* __restrict__ h, const float* __restrict__ Wo,
    const float* __restrict__ bo, float* __restrict__ out, int N)
{
    int n = blockIdx.x * 256 + threadIdx.x;
    if (n >= N) return;
    const float4* hrow = reinterpret_cast<const float4*>(h + (size_t)n * DD);
    float acc = bo[0];
    #pragma unroll
    for (int kk = 0; kk < DD / 4; ++kk) {
        float4 a = hrow[kk];
        acc += a.x * Wo[4*kk] + a.y * Wo[4*kk+1] + a.z * Wo[4*kk+2] + a.w * Wo[4*kk+3];
    }
    out[n] = acc;
}

extern "C" void kernel_launch(void* const* d_in, const int* in_sizes, int n_in,
                              void* d_out, int out_size, void* d_ws, size_t ws_size,
                              hipStream_t stream) {
    const float* node = (const float*)d_in[0];
    const float* ef   = (const float*)d_in[1];
    const int*   src  = (const int*)d_in[2];
    const int*   dst  = (const int*)d_in[3];
    const float* Wm1  = (const float*)d_in[4];
    const float* bm1  = (const float*)d_in[5];
    const float* Wu1  = (const float*)d_in[6];
    const float* bu1  = (const float*)d_in[7];
    const float* Wm2  = (const float*)d_in[8];
    const float* bm2  = (const float*)d_in[9];
    const float* Wu2  = (const float*)d_in[10];
    const float* bu2  = (const float*)d_in[11];
    const float* Wo   = (const float*)d_in[12];
    const float* bo   = (const float*)d_in[13];
    float* out = (float*)d_out;

    const int N = in_sizes[0] / DD;
    const int E = in_sizes[2];

    // ws layout
    char* p = (char*)d_ws;
    float* h1     = (float*)p; p += (size_t)N * DD * 4;
    float* h2     = (float*)p; p += (size_t)N * DD * 4;
    float* hm     = (float*)p; p += (size_t)N * DD * 4;
    float* pooled = (float*)p; p += (size_t)N * DD * 4;
    unsigned short* efb  = (unsigned short*)p; p += (size_t)E * DD * 2;
    unsigned short* wt1b = (unsigned short*)p; p += (size_t)DD * DD * 2;
    unsigned short* wt2b = (unsigned short*)p; p += (size_t)DD * DD * 2;
    int*   deg    = (int*)p;   p += (size_t)N * 4;
    int*   off    = (int*)p;   p += (size_t)(N + 1) * 4;
    int*   cursor = (int*)p;   p += (size_t)N * 4;
    int*   eidx   = (int*)p;   p += (size_t)E * 4;
    size_t needed = (size_t)(p - (char*)d_ws);

    dim3 blk(256);
    int nbN = (N + 255) / 256;
    int nbE = (E + 255) / 256;

    if (ws_size >= needed) {
        // ---- CSR build + weight prep (stateless: rebuilt every call) ----
        hipMemsetAsync(deg, 0, (size_t)N * 4, stream);
        count_deg<<<nbE, blk, 0, stream>>>(dst, deg, E);
        scan_kernel<<<1, 1024, 0, stream>>>(deg, off, cursor, N);
        fill_eidx<<<nbE, blk, 0, stream>>>(dst, cursor, eidx, E);
        prep_wt<<<32, blk, 0, stream>>>(Wm1, Wm2, wt1b, wt2b);

        // ---- layer 1 ----
        node_transform<<<nbN, blk, 0, stream>>>(node, Wm1, bm1, hm, pooled, N);
        fused_edge_gather<<<nbE, blk, 0, stream>>>(ef, efb, hm, src, dst, off, eidx,
                                                   wt1b, pooled, E, N, 1);
        update_kernel<<<nbN, blk, 0, stream>>>(node, pooled, Wu1, bu1, h1, N);

        // ---- layer 2 ----
        node_transform<<<nbN, blk, 0, stream>>>(h1, Wm2, bm2, hm, pooled, N);
        fused_edge_gather<<<nbE, blk, 0, stream>>>(ef, efb, hm, src, dst, off, eidx,
                                                   wt2b, pooled, E, N, 0);
        update_kernel<<<nbN, blk, 0, stream>>>(h1, pooled, Wu2, bu2, h2, N);
    } else {
        // ---- fallback: atomic scatter path (fp32 exact) ----
        node_transform<<<nbN, blk, 0, stream>>>(node, Wm1, bm1, hm, pooled, N);
        edge_kernel_atomic<<<nbE, blk, 0, stream>>>(ef, hm, src, dst, Wm1 + DD * DD, pooled, E);
        update_kernel<<<nbN, blk, 0, stream>>>(node, pooled, Wu1, bu1, h1, N);

        node_transform<<<nbN, blk, 0, stream>>>(h1, Wm2, bm2, hm, pooled, N);
        edge_kernel_atomic<<<nbE, blk, 0, stream>>>(ef, hm, src, dst, Wm2 + DD * DD, pooled, E);
        update_kernel<<<nbN, blk, 0, stream>>>(h1, pooled, Wu2, bu2, h2, N);
    }

    // ---- readout ----
    out_kernel<<<nbN, blk, 0, stream>>>(h2, Wo, bo, out, N);
}

// Round 8
// 476.667 us; speedup vs baseline: 2.3357x; 1.5110x over previous
//
#include <hip/hip_runtime.h>

#define DD 64

typedef __attribute__((ext_vector_type(8))) short bf16x8;
typedef __attribute__((ext_vector_type(4))) float f32x4;

__device__ __forceinline__ float fast_tanh(float x) {
    float e = __builtin_amdgcn_exp2f(x * 2.885390081777927f); // 2x * log2(e)
    return 1.0f - 2.0f * __builtin_amdgcn_rcpf(e + 1.0f);
}

__device__ __forceinline__ unsigned f2bf(float f) {
    union { float f; unsigned u; } v; v.f = f;
    return (v.u + 0x7FFFu + ((v.u >> 16) & 1u)) >> 16;   // RNE
}

// ---------------- CSR build ----------------

__global__ void __launch_bounds__(256) count_deg(
    const int* __restrict__ dst, int* __restrict__ deg, int E)
{
    int e = blockIdx.x * 256 + threadIdx.x;
    if (e < E) atomicAdd(&deg[dst[e]], 1);
}

__global__ void __launch_bounds__(1024) scan_kernel(
    const int* __restrict__ deg, int* __restrict__ off,
    int* __restrict__ cursor, int N)
{
    __shared__ int part[1024];
    int t = threadIdx.x;
    int per = (N + 1023) / 1024;
    int lo = t * per;
    int hi = lo + per; if (hi > N) hi = N;
    int s = 0;
    for (int i = lo; i < hi; ++i) s += deg[i];
    part[t] = s;
    __syncthreads();
    for (int d = 1; d < 1024; d <<= 1) {
        int v = 0;
        if (t >= d) v = part[t - d];
        __syncthreads();
        if (t >= d) part[t] += v;
        __syncthreads();
    }
    int run = (t == 0) ? 0 : part[t - 1];
    for (int i = lo; i < hi; ++i) {
        off[i] = run; cursor[i] = run;
        run += deg[i];
    }
    if (lo < N && hi == N) off[N] = run;
}

__global__ void __launch_bounds__(256) fill_eidx(
    const int* __restrict__ dst, int* __restrict__ cursor,
    int* __restrict__ eidx, int E)
{
    int e = blockIdx.x * 256 + threadIdx.x;
    if (e < E) {
        int slot = atomicAdd(&cursor[dst[e]], 1);
        eidx[slot] = e;
    }
}

// wt[m][n*64+k] = bf16(W_m[(koff+k)*64 + n]) for the 8 half-matrices:
// 0:Wm1 top  1:Wm1 bot  2:Wu1 top  3:Wu1 bot  4:Wm2 top  5:Wm2 bot  6:Wu2 top  7:Wu2 bot
__global__ void __launch_bounds__(256) prep_wt_all(
    const float* __restrict__ Wm1, const float* __restrict__ Wu1,
    const float* __restrict__ Wm2, const float* __restrict__ Wu2,
    unsigned short* __restrict__ wt)
{
    int i = blockIdx.x * 256 + threadIdx.x;
    if (i >= 8 * 4096) return;
    int m = i >> 12;
    int j = i & 4095;
    int n = j >> 6, k = j & 63;
    const float* W; int koff;
    switch (m) {
        case 0: W = Wm1; koff = 0;  break;
        case 1: W = Wm1; koff = 64; break;
        case 2: W = Wu1; koff = 0;  break;
        case 3: W = Wu1; koff = 64; break;
        case 4: W = Wm2; koff = 0;  break;
        case 5: W = Wm2; koff = 64; break;
        case 6: W = Wu2; koff = 0;  break;
        default: W = Wu2; koff = 64; break;
    }
    wt[i] = (unsigned short)f2bf(W[(koff + k) * 64 + n]);
}

// ---------------- MFMA node GEMM ----------------
// out[r] = op(A1[r]@W1 (+ A2[r]@W2) + bias), 128 rows/block, 4 waves.
// Fragment scheme identical to the (verified) fused edge kernel.
template<bool TWO, bool TANH, bool ZEROP>
__global__ void __launch_bounds__(256, 2) node_mfma(
    const float* __restrict__ A1, const float* __restrict__ A2,
    const unsigned short* __restrict__ wt1, const unsigned short* __restrict__ wt2,
    const float* __restrict__ bias, float* __restrict__ outp,
    float* __restrict__ pooled, int N)
{
    __shared__ unsigned short ldsA1[128 * 64];
    __shared__ unsigned short ldsA2[TWO ? 128 * 64 : 8];
    __shared__ unsigned short ldsW1[64 * 64];
    __shared__ unsigned short ldsW2[TWO ? 64 * 64 : 8];

    const int t = threadIdx.x;
    const int row0 = blockIdx.x * 128;
    const int wv = t >> 6, l = t & 63;
    const int lrow = l & 15, lk = l >> 4;

    // stage W(s): thread t -> row n=t>>2, 2 chunks of 8 bf16
    {
        int n = t >> 2, c0 = (t & 3) * 2;
        const uint4* w1 = reinterpret_cast<const uint4*>(wt1 + n * 64);
        #pragma unroll
        for (int i = 0; i < 2; ++i) {
            int cc = c0 + i;
            *reinterpret_cast<uint4*>(&ldsW1[(n * 8 + (cc ^ (n & 7))) * 8]) = w1[cc];
        }
        if (TWO) {
            const uint4* w2 = reinterpret_cast<const uint4*>(wt2 + n * 64);
            #pragma unroll
            for (int i = 0; i < 2; ++i) {
                int cc = c0 + i;
                *reinterpret_cast<uint4*>(&ldsW2[(n * 8 + (cc ^ (n & 7))) * 8]) = w2[cc];
            }
        }
    }

    // stage A tile(s): r = t>>1, half = t&1, fp32 -> bf16 swizzled
    {
        int r = t >> 1, half = t & 1;
        int grow = row0 + r;
        if (grow < N) {
            const float4* a4 = reinterpret_cast<const float4*>(A1 + (size_t)grow * 64) + half * 8;
            #pragma unroll
            for (int c = 0; c < 4; ++c) {
                float4 f0 = a4[c * 2], f1 = a4[c * 2 + 1];
                uint4 chv;
                chv.x = f2bf(f0.x) | (f2bf(f0.y) << 16);
                chv.y = f2bf(f0.z) | (f2bf(f0.w) << 16);
                chv.z = f2bf(f1.x) | (f2bf(f1.y) << 16);
                chv.w = f2bf(f1.z) | (f2bf(f1.w) << 16);
                int cc = half * 4 + c;
                *reinterpret_cast<uint4*>(&ldsA1[(r * 8 + (cc ^ (r & 7))) * 8]) = chv;
            }
            if (TWO) {
                const float4* b4 = reinterpret_cast<const float4*>(A2 + (size_t)grow * 64) + half * 8;
                #pragma unroll
                for (int c = 0; c < 4; ++c) {
                    float4 f0 = b4[c * 2], f1 = b4[c * 2 + 1];
                    uint4 chv;
                    chv.x = f2bf(f0.x) | (f2bf(f0.y) << 16);
                    chv.y = f2bf(f0.z) | (f2bf(f0.w) << 16);
                    chv.z = f2bf(f1.x) | (f2bf(f1.y) << 16);
                    chv.w = f2bf(f1.z) | (f2bf(f1.w) << 16);
                    int cc = half * 4 + c;
                    *reinterpret_cast<uint4*>(&ldsA2[(r * 8 + (cc ^ (r & 7))) * 8]) = chv;
                }
            }
        } else {
            uint4 z = make_uint4(0, 0, 0, 0);
            #pragma unroll
            for (int c = 0; c < 4; ++c) {
                int cc = half * 4 + c;
                *reinterpret_cast<uint4*>(&ldsA1[(r * 8 + (cc ^ (r & 7))) * 8]) = z;
                if (TWO) *reinterpret_cast<uint4*>(&ldsA2[(r * 8 + (cc ^ (r & 7))) * 8]) = z;
            }
        }
    }
    __syncthreads();

    // B fragments
    bf16x8 bfr1[4][2], bfr2[4][2];
    #pragma unroll
    for (int cg = 0; cg < 4; ++cg) {
        int n = cg * 16 + lrow;
        #pragma unroll
        for (int k2 = 0; k2 < 2; ++k2) {
            int kc = lk + k2 * 4;
            bfr1[cg][k2] = *reinterpret_cast<const bf16x8*>(&ldsW1[(n * 8 + (kc ^ (n & 7))) * 8]);
            if (TWO)
                bfr2[cg][k2] = *reinterpret_cast<const bf16x8*>(&ldsW2[(n * 8 + (kc ^ (n & 7))) * 8]);
        }
    }

    f32x4 acc[2][4];
    #pragma unroll
    for (int er = 0; er < 2; ++er) {
        int row = wv * 32 + er * 16 + lrow;
        bf16x8 a0 = *reinterpret_cast<const bf16x8*>(&ldsA1[(row * 8 + ((lk + 0) ^ (row & 7))) * 8]);
        bf16x8 a1 = *reinterpret_cast<const bf16x8*>(&ldsA1[(row * 8 + ((lk + 4) ^ (row & 7))) * 8]);
        #pragma unroll
        for (int cg = 0; cg < 4; ++cg) {
            f32x4 zz = {0.f, 0.f, 0.f, 0.f};
            acc[er][cg] = __builtin_amdgcn_mfma_f32_16x16x32_bf16(a0, bfr1[cg][0], zz, 0, 0, 0);
            acc[er][cg] = __builtin_amdgcn_mfma_f32_16x16x32_bf16(a1, bfr1[cg][1], acc[er][cg], 0, 0, 0);
        }
        if (TWO) {
            bf16x8 c0 = *reinterpret_cast<const bf16x8*>(&ldsA2[(row * 8 + ((lk + 0) ^ (row & 7))) * 8]);
            bf16x8 c1 = *reinterpret_cast<const bf16x8*>(&ldsA2[(row * 8 + ((lk + 4) ^ (row & 7))) * 8]);
            #pragma unroll
            for (int cg = 0; cg < 4; ++cg) {
                acc[er][cg] = __builtin_amdgcn_mfma_f32_16x16x32_bf16(c0, bfr2[cg][0], acc[er][cg], 0, 0, 0);
                acc[er][cg] = __builtin_amdgcn_mfma_f32_16x16x32_bf16(c1, bfr2[cg][1], acc[er][cg], 0, 0, 0);
            }
        }
    }

    // epilogue: C/D mapping col=lane&15, row=(lane>>4)*4+reg (verified)
    #pragma unroll
    for (int er = 0; er < 2; ++er) {
        int rbase = row0 + wv * 32 + er * 16 + (lk << 2);
        #pragma unroll
        for (int cg = 0; cg < 4; ++cg) {
            int col = cg * 16 + lrow;
            float bv = bias[col];
            #pragma unroll
            for (int j = 0; j < 4; ++j) {
                int r = rbase + j;
                if (r < N) {
                    float v = acc[er][cg][j] + bv;
                    if (TANH) v = fast_tanh(v);
                    outp[(size_t)r * 64 + col] = v;
                    if (ZEROP) pooled[(size_t)r * 64 + col] = 0.f;
                }
            }
        }
    }
}

// ---------------- MFMA fused edge kernel (verified round 7) ----------------
__global__ void __launch_bounds__(256, 2) fused_edge_gather(
    const float* __restrict__ ef, unsigned short* __restrict__ efb,
    const float* __restrict__ hm,
    const int* __restrict__ src, const int* __restrict__ dst,
    const int* __restrict__ off, const int* __restrict__ eidx,
    const unsigned short* __restrict__ wtb, float* __restrict__ pooled,
    int E, int N, int layer1)
{
    __shared__ unsigned short ldsW[64 * 64];
    __shared__ unsigned short ldsA[128 * 64];
    __shared__ float ldsM[128 * 66];
    __shared__ int   ldsSrc[128];

    const int t  = threadIdx.x;
    const int s0 = blockIdx.x * 256;
    const int wv = t >> 6, l = t & 63;
    const int lrow = l & 15, lk = l >> 4;

    {
        int n = t >> 2, c0 = (t & 3) * 2;
        const uint4* wb = reinterpret_cast<const uint4*>(wtb + n * 64);
        #pragma unroll
        for (int i = 0; i < 2; ++i) {
            int cc = c0 + i;
            *reinterpret_cast<uint4*>(&ldsW[(n * 8 + (cc ^ (n & 7))) * 8]) = wb[cc];
        }
    }

#define STAGE_A(CK)                                                            \
    {                                                                          \
        int cb = s0 + (CK) * 128;                                              \
        int r = t >> 1, half = t & 1;                                          \
        int slot = cb + r;                                                     \
        if (slot < E) {                                                        \
            int e = eidx[slot];                                                \
            if (half == 0) ldsSrc[r] = src[e];                                 \
            if (layer1) {                                                      \
                const float4* er4 =                                            \
                    reinterpret_cast<const float4*>(ef + (size_t)e * 64) + half * 8; \
                uint4* gout =                                                  \
                    reinterpret_cast<uint4*>(efb + (size_t)slot * 64) + half * 4; \
                _Pragma("unroll")                                              \
                for (int c = 0; c < 4; ++c) {                                  \
                    float4 f0 = er4[c * 2], f1 = er4[c * 2 + 1];               \
                    uint4 chv;                                                 \
                    chv.x = f2bf(f0.x) | (f2bf(f0.y) << 16);                   \
                    chv.y = f2bf(f0.z) | (f2bf(f0.w) << 16);                   \
                    chv.z = f2bf(f1.x) | (f2bf(f1.y) << 16);                   \
                    chv.w = f2bf(f1.z) | (f2bf(f1.w) << 16);                   \
                    int cc = half * 4 + c;                                     \
                    *reinterpret_cast<uint4*>(&ldsA[(r * 8 + (cc ^ (r & 7))) * 8]) = chv; \
                    gout[c] = chv;                                             \
                }                                                              \
            } else {                                                           \
                const uint4* eb4 =                                             \
                    reinterpret_cast<const uint4*>(efb + (size_t)slot * 64) + half * 4; \
                _Pragma("unroll")                                              \
                for (int c = 0; c < 4; ++c) {                                  \
                    uint4 chv = eb4[c];                                        \
                    int cc = half * 4 + c;                                     \
                    *reinterpret_cast<uint4*>(&ldsA[(r * 8 + (cc ^ (r & 7))) * 8]) = chv; \
                }                                                              \
            }                                                                  \
        } else {                                                               \
            if (half == 0) ldsSrc[r] = 0;                                      \
            uint4 z = make_uint4(0, 0, 0, 0);                                  \
            _Pragma("unroll")                                                  \
            for (int c = 0; c < 4; ++c) {                                      \
                int cc = half * 4 + c;                                         \
                *reinterpret_cast<uint4*>(&ldsA[(r * 8 + (cc ^ (r & 7))) * 8]) = z; \
            }                                                                  \
        }                                                                      \
    }

#define COMPUTE(CK)                                                            \
    {                                                                          \
        bf16x8 afr[2][2];                                                      \
        _Pragma("unroll")                                                      \
        for (int er = 0; er < 2; ++er) {                                       \
            int row = wv * 32 + er * 16 + lrow;                                \
            _Pragma("unroll")                                                  \
            for (int k2 = 0; k2 < 2; ++k2) {                                   \
                int kc = lk + k2 * 4;                                          \
                afr[er][k2] = *reinterpret_cast<const bf16x8*>(                \
                    &ldsA[(row * 8 + (kc ^ (row & 7))) * 8]);                  \
            }                                                                  \
        }                                                                      \
        f32x4 acc[2][4];                                                       \
        _Pragma("unroll")                                                      \
        for (int er = 0; er < 2; ++er)                                         \
        {                                                                      \
            _Pragma("unroll")                                                  \
            for (int cg = 0; cg < 4; ++cg) {                                   \
                f32x4 z = {0.f, 0.f, 0.f, 0.f};                                \
                acc[er][cg] = __builtin_amdgcn_mfma_f32_16x16x32_bf16(         \
                    afr[er][0], bfr[cg][0], z, 0, 0, 0);                       \
                acc[er][cg] = __builtin_amdgcn_mfma_f32_16x16x32_bf16(         \
                    afr[er][1], bfr[cg][1], acc[er][cg], 0, 0, 0);             \
            }                                                                  \
        }                                                                      \
        _Pragma("unroll")                                                      \
        for (int er = 0; er < 2; ++er) {                                       \
            int rbase = wv * 32 + er * 16 + (lk << 2);                         \
            int sA = ldsSrc[rbase + 0], sB = ldsSrc[rbase + 1];                \
            int sC = ldsSrc[rbase + 2], sD = ldsSrc[rbase + 3];                \
            _Pragma("unroll")                                                  \
            for (int cg = 0; cg < 4; ++cg) {                                   \
                int col = cg * 16 + lrow;                                      \
                float hA = hm[(size_t)sA * 64 + col];                          \
                float hB = hm[(size_t)sB * 64 + col];                          \
                float hC = hm[(size_t)sC * 64 + col];                          \
                float hD = hm[(size_t)sD * 64 + col];                          \
                ldsM[(rbase + 0) * 66 + col] = fast_tanh(acc[er][cg][0] + hA); \
                ldsM[(rbase + 1) * 66 + col] = fast_tanh(acc[er][cg][1] + hB); \
                ldsM[(rbase + 2) * 66 + col] = fast_tanh(acc[er][cg][2] + hC); \
                ldsM[(rbase + 3) * 66 + col] = fast_tanh(acc[er][cg][3] + hD); \
            }                                                                  \
        }                                                                      \
    }

#define PHASE2(CK)                                                             \
    {                                                                          \
        int cb = s0 + (CK) * 128;                                              \
        int ce = cb + 128; if (ce > E) ce = E;                                 \
        if (cb < E) {                                                          \
            int df = dst[eidx[cb]];                                            \
            int dl = dst[eidx[ce - 1]];                                        \
            for (int n = df + wv; n <= dl; n += 4) {                           \
                int lo = off[n], hi = off[n + 1];                              \
                int clo = lo > cb ? lo : cb;                                   \
                int chi = hi < ce ? hi : ce;                                   \
                if (clo >= chi) continue;                                      \
                float v = 0.f;                                                 \
                for (int q = clo; q < chi; ++q) v += ldsM[(q - cb) * 66 + l];  \
                if (lo >= cb && hi <= ce) pooled[(size_t)n * 64 + l] = v;      \
                else atomicAdd(pooled + (size_t)n * 64 + l, v);                \
            }                                                                  \
        }                                                                      \
    }

    STAGE_A(0)
    __syncthreads();

    bf16x8 bfr[4][2];
    #pragma unroll
    for (int cg = 0; cg < 4; ++cg) {
        int n = cg * 16 + lrow;
        #pragma unroll
        for (int k2 = 0; k2 < 2; ++k2) {
            int kc = lk + k2 * 4;
            bfr[cg][k2] = *reinterpret_cast<const bf16x8*>(
                &ldsW[(n * 8 + (kc ^ (n & 7))) * 8]);
        }
    }

    COMPUTE(0)
    __syncthreads();
    STAGE_A(1)
    PHASE2(0)
    __syncthreads();
    COMPUTE(1)
    __syncthreads();
    PHASE2(1)

#undef STAGE_A
#undef COMPUTE
#undef PHASE2
}

// ---------------- scalar fallback kernels (ws too small; fp32 exact) ----------------

__global__ void __launch_bounds__(256, 2) node_transform(
    const float* __restrict__ h, const float* __restrict__ W,
    const float* __restrict__ b, float* __restrict__ hm,
    float* __restrict__ pooled, int N)
{
    int n = blockIdx.x * 256 + threadIdx.x;
    if (n >= N) return;
    float acc[DD];
    #pragma unroll
    for (int j = 0; j < DD; ++j) acc[j] = b[j];
    const float4* hrow = reinterpret_cast<const float4*>(h + (size_t)n * DD);
    #pragma unroll
    for (int kk = 0; kk < DD / 4; ++kk) {
        float4 a = hrow[kk];
        const float* Wr = W + kk * 4 * DD;
        #pragma unroll
        for (int j = 0; j < DD; ++j)
            acc[j] += a.x * Wr[j] + a.y * Wr[DD + j]
                    + a.z * Wr[2 * DD + j] + a.w * Wr[3 * DD + j];
    }
    float4* orow = reinterpret_cast<float4*>(hm + (size_t)n * DD);
    float4* prow = reinterpret_cast<float4*>(pooled + (size_t)n * DD);
    #pragma unroll
    for (int jj = 0; jj < DD / 4; ++jj) {
        orow[jj] = make_float4(acc[4*jj], acc[4*jj+1], acc[4*jj+2], acc[4*jj+3]);
        prow[jj] = make_float4(0.f, 0.f, 0.f, 0.f);
    }
}

__global__ void __launch_bounds__(256, 2) edge_kernel_atomic(
    const float* __restrict__ ef, const float* __restrict__ hm,
    const int* __restrict__ src, const int* __restrict__ dst,
    const float* __restrict__ W, float* __restrict__ pooled, int E)
{
    int e = blockIdx.x * 256 + threadIdx.x;
    if (e >= E) return;
    int s = src[e];
    int d = dst[e];
    float acc[DD];
    #pragma unroll
    for (int j = 0; j < DD; ++j) acc[j] = 0.0f;
    const float4* erow = reinterpret_cast<const float4*>(ef + (size_t)e * DD);
    #pragma unroll
    for (int kk = 0; kk < DD / 4; ++kk) {
        float4 a = erow[kk];
        const float* Wr = W + kk * 4 * DD;
        #pragma unroll
        for (int j = 0; j < DD; ++j)
            acc[j] += a.x * Wr[j] + a.y * Wr[DD + j]
                    + a.z * Wr[2 * DD + j] + a.w * Wr[3 * DD + j];
    }
    const float4* hrow = reinterpret_cast<const float4*>(hm + (size_t)s * DD);
    float* prow = pooled + (size_t)d * DD;
    #pragma unroll
    for (int jj = 0; jj < DD / 4; ++jj) {
        float4 hv = hrow[jj];
        atomicAdd(prow + 4*jj + 0, fast_tanh(acc[4*jj+0] + hv.x));
        atomicAdd(prow + 4*jj + 1, fast_tanh(acc[4*jj+1] + hv.y));
        atomicAdd(prow + 4*jj + 2, fast_tanh(acc[4*jj+2] + hv.z));
        atomicAdd(prow + 4*jj + 3, fast_tanh(acc[4*jj+3] + hv.w));
    }
}

__global__ void __launch_bounds__(256, 2) update_kernel(
    const float* __restrict__ h, const float* __restrict__ pooled,
    const float* __restrict__ Wu, const float* __restrict__ bu,
    float* __restrict__ hout, int N)
{
    int n = blockIdx.x * 256 + threadIdx.x;
    if (n >= N) return;
    float acc[DD];
    #pragma unroll
    for (int j = 0; j < DD; ++j) acc[j] = bu[j];
    const float4* hrow = reinterpret_cast<const float4*>(h + (size_t)n * DD);
    #pragma unroll
    for (int kk = 0; kk < DD / 4; ++kk) {
        float4 a = hrow[kk];
        const float* Wr = Wu + kk * 4 * DD;
        #pragma unroll
        for (int j = 0; j < DD; ++j)
            acc[j] += a.x * Wr[j] + a.y * Wr[DD + j]
                    + a.z * Wr[2 * DD + j] + a.w * Wr[3 * DD + j];
    }
    const float4* prow = reinterpret_cast<const float4*>(pooled + (size_t)n * DD);
    #pragma unroll
    for (int kk = 0; kk < DD / 4; ++kk) {
        float4 a = prow[kk];
        const float* Wr = Wu + (DD + kk * 4) * DD;
        #pragma unroll
        for (int j = 0; j < DD; ++j)
            acc[j] += a.x * Wr[j] + a.y * Wr[DD + j]
                    + a.z * Wr[2 * DD + j] + a.w * Wr[3 * DD + j];
    }
    float4* orow = reinterpret_cast<float4*>(hout + (size_t)n * DD);
    #pragma unroll
    for (int jj = 0; jj < DD / 4; ++jj)
        orow[jj] = make_float4(fast_tanh(acc[4*jj]),   fast_tanh(acc[4*jj+1]),
                               fast_tanh(acc[4*jj+2]), fast_tanh(acc[4*jj+3]));
}

__global__ void __launch_bounds__(256) out_kernel(
    const float* __restrict__ h, const float* __restrict__ Wo,
    const float* __restrict__ bo, float* __restrict__ out, int N)
{
    int n = blockIdx.x * 256 + threadIdx.x;
    if (n >= N) return;
    const float4* hrow = reinterpret_cast<const float4*>(h + (size_t)n * DD);
    float acc = bo[0];
    #pragma unroll
    for (int kk = 0; kk < DD / 4; ++kk) {
        float4 a = hrow[kk];
        acc += a.x * Wo[4*kk] + a.y * Wo[4*kk+1] + a.z * Wo[4*kk+2] + a.w * Wo[4*kk+3];
    }
    out[n] = acc;
}

extern "C" void kernel_launch(void* const* d_in, const int* in_sizes, int n_in,
                              void* d_out, int out_size, void* d_ws, size_t ws_size,
                              hipStream_t stream) {
    const float* node = (const float*)d_in[0];
    const float* ef   = (const float*)d_in[1];
    const int*   src  = (const int*)d_in[2];
    const int*   dst  = (const int*)d_in[3];
    const float* Wm1  = (const float*)d_in[4];
    const float* bm1  = (const float*)d_in[5];
    const float* Wu1  = (const float*)d_in[6];
    const float* bu1  = (const float*)d_in[7];
    const float* Wm2  = (const float*)d_in[8];
    const float* bm2  = (const float*)d_in[9];
    const float* Wu2  = (const float*)d_in[10];
    const float* bu2  = (const float*)d_in[11];
    const float* Wo   = (const float*)d_in[12];
    const float* bo   = (const float*)d_in[13];
    float* out = (float*)d_out;

    const int N = in_sizes[0] / DD;
    const int E = in_sizes[2];

    // ws layout
    char* p = (char*)d_ws;
    float* h1     = (float*)p; p += (size_t)N * DD * 4;
    float* h2     = (float*)p; p += (size_t)N * DD * 4;
    float* hm     = (float*)p; p += (size_t)N * DD * 4;
    float* pooled = (float*)p; p += (size_t)N * DD * 4;
    unsigned short* efb = (unsigned short*)p; p += (size_t)E * DD * 2;
    unsigned short* wt  = (unsigned short*)p; p += (size_t)8 * DD * DD * 2;
    int*   deg    = (int*)p;   p += (size_t)N * 4;
    int*   off    = (int*)p;   p += (size_t)(N + 1) * 4;
    int*   cursor = (int*)p;   p += (size_t)N * 4;
    int*   eidx   = (int*)p;   p += (size_t)E * 4;
    size_t needed = (size_t)(p - (char*)d_ws);

    dim3 blk(256);
    int nbN = (N + 255) / 256;
    int nbE = (E + 255) / 256;
    int nbT = (N + 127) / 128;

    if (ws_size >= needed) {
        // ---- CSR build + weight prep (stateless: rebuilt every call) ----
        hipMemsetAsync(deg, 0, (size_t)N * 4, stream);
        count_deg<<<nbE, blk, 0, stream>>>(dst, deg, E);
        scan_kernel<<<1, 1024, 0, stream>>>(deg, off, cursor, N);
        fill_eidx<<<nbE, blk, 0, stream>>>(dst, cursor, eidx, E);
        prep_wt_all<<<128, blk, 0, stream>>>(Wm1, Wu1, Wm2, Wu2, wt);

        // ---- layer 1 ----
        node_mfma<false, false, true><<<nbT, blk, 0, stream>>>(
            node, nullptr, wt + 0 * 4096, nullptr, bm1, hm, pooled, N);
        fused_edge_gather<<<nbE, blk, 0, stream>>>(ef, efb, hm, src, dst, off, eidx,
                                                   wt + 1 * 4096, pooled, E, N, 1);
        node_mfma<true, true, false><<<nbT, blk, 0, stream>>>(
            node, pooled, wt + 2 * 4096, wt + 3 * 4096, bu1, h1, nullptr, N);

        // ---- layer 2 ----
        node_mfma<false, false, true><<<nbT, blk, 0, stream>>>(
            h1, nullptr, wt + 4 * 4096, nullptr, bm2, hm, pooled, N);
        fused_edge_gather<<<nbE, blk, 0, stream>>>(ef, efb, hm, src, dst, off, eidx,
                                                   wt + 5 * 4096, pooled, E, N, 0);
        node_mfma<true, true, false><<<nbT, blk, 0, stream>>>(
            h1, pooled, wt + 6 * 4096, wt + 7 * 4096, bu2, h2, nullptr, N);
    } else {
        // ---- fallback: atomic scatter path (fp32 exact) ----
        node_transform<<<nbN, blk, 0, stream>>>(node, Wm1, bm1, hm, pooled, N);
        edge_kernel_atomic<<<nbE, blk, 0, stream>>>(ef, hm, src, dst, Wm1 + DD * DD, pooled, E);
        update_kernel<<<nbN, blk, 0, stream>>>(node, pooled, Wu1, bu1, h1, N);

        node_transform<<<nbN, blk, 0, stream>>>(h1, Wm2, bm2, hm, pooled, N);
        edge_kernel_atomic<<<nbE, blk, 0, stream>>>(ef, hm, src, dst, Wm2 + DD * DD, pooled, E);
        update_kernel<<<nbN, blk, 0, stream>>>(h1, pooled, Wu2, bu2, h2, N);
    }

    // ---- readout ----
    out_kernel<<<nbN, blk, 0, stream>>>(h2, Wo, bo, out, N);
}

// Round 9
// 441.801 us; speedup vs baseline: 2.5201x; 1.0789x over previous
//
#include <hip/hip_runtime.h>

#define DD 64

typedef __attribute__((ext_vector_type(8))) short bf16x8;
typedef __attribute__((ext_vector_type(4))) float f32x4;

__device__ __forceinline__ float fast_tanh(float x) {
    float e = __builtin_amdgcn_exp2f(x * 2.885390081777927f); // 2x * log2(e)
    return 1.0f - 2.0f * __builtin_amdgcn_rcpf(e + 1.0f);
}

__device__ __forceinline__ unsigned f2bf(float f) {
    union { float f; unsigned u; } v; v.f = f;
    return (v.u + 0x7FFFu + ((v.u >> 16) & 1u)) >> 16;   // RNE
}

__device__ __forceinline__ float bf2f(unsigned short u) {
    union { unsigned u; float f; } v; v.u = ((unsigned)u) << 16;
    return v.f;
}

__device__ __forceinline__ bf16x8 cvt8(float4 f0, float4 f1) {
    union { unsigned u[4]; bf16x8 v; } r;
    r.u[0] = f2bf(f0.x) | (f2bf(f0.y) << 16);
    r.u[1] = f2bf(f0.z) | (f2bf(f0.w) << 16);
    r.u[2] = f2bf(f1.x) | (f2bf(f1.y) << 16);
    r.u[3] = f2bf(f1.z) | (f2bf(f1.w) << 16);
    return r.v;
}

// ---------------- CSR build ----------------

__global__ void __launch_bounds__(256) count_deg(
    const int* __restrict__ dst, int* __restrict__ deg, int E)
{
    int e = blockIdx.x * 256 + threadIdx.x;
    if (e < E) atomicAdd(&deg[dst[e]], 1);
}

__global__ void __launch_bounds__(1024) scan_kernel(
    const int* __restrict__ deg, int* __restrict__ off,
    int* __restrict__ cursor, int N)
{
    __shared__ int part[1024];
    int t = threadIdx.x;
    int per = (N + 1023) / 1024;
    int lo = t * per;
    int hi = lo + per; if (hi > N) hi = N;
    int s = 0;
    for (int i = lo; i < hi; ++i) s += deg[i];
    part[t] = s;
    __syncthreads();
    for (int d = 1; d < 1024; d <<= 1) {
        int v = 0;
        if (t >= d) v = part[t - d];
        __syncthreads();
        if (t >= d) part[t] += v;
        __syncthreads();
    }
    int run = (t == 0) ? 0 : part[t - 1];
    for (int i = lo; i < hi; ++i) {
        off[i] = run; cursor[i] = run;
        run += deg[i];
    }
    if (lo < N && hi == N) off[N] = run;
}

__global__ void __launch_bounds__(256) fill_eidx(
    const int* __restrict__ dst, int* __restrict__ cursor,
    int* __restrict__ eidx, int E)
{
    int e = blockIdx.x * 256 + threadIdx.x;
    if (e < E) {
        int slot = atomicAdd(&cursor[dst[e]], 1);
        eidx[slot] = e;
    }
}

// wt[m][n*64+k] = bf16(W_m[(koff+k)*64 + n]) for the 8 half-matrices:
// 0:Wm1 top  1:Wm1 bot  2:Wu1 top  3:Wu1 bot  4:Wm2 top  5:Wm2 bot  6:Wu2 top  7:Wu2 bot
__global__ void __launch_bounds__(256) prep_wt_all(
    const float* __restrict__ Wm1, const float* __restrict__ Wu1,
    const float* __restrict__ Wm2, const float* __restrict__ Wu2,
    unsigned short* __restrict__ wt)
{
    int i = blockIdx.x * 256 + threadIdx.x;
    if (i >= 8 * 4096) return;
    int m = i >> 12;
    int j = i & 4095;
    int n = j >> 6, k = j & 63;
    const float* W; int koff;
    switch (m) {
        case 0: W = Wm1; koff = 0;  break;
        case 1: W = Wm1; koff = 64; break;
        case 2: W = Wu1; koff = 0;  break;
        case 3: W = Wu1; koff = 64; break;
        case 4: W = Wm2; koff = 0;  break;
        case 5: W = Wm2; koff = 64; break;
        case 6: W = Wu2; koff = 0;  break;
        default: W = Wu2; koff = 64; break;
    }
    wt[i] = (unsigned short)f2bf(W[(koff + k) * 64 + n]);
}

// ---------------- MFMA node GEMM (no LDS: direct fragment loads) ----------------
// out[r] = op(A1[r]@W1 (+ A2[r]@W2) + bias), 128 rows/block, 4 waves.
template<bool TWO, bool TANH, bool ZEROP>
__global__ void __launch_bounds__(256, 4) node_mfma(
    const float* __restrict__ A1, const float* __restrict__ A2,
    const unsigned short* __restrict__ wt1, const unsigned short* __restrict__ wt2,
    const float* __restrict__ bias, float* __restrict__ outp,
    float* __restrict__ pooled, int N)
{
    const int t = threadIdx.x;
    const int row0 = blockIdx.x * 128;
    const int wv = t >> 6, l = t & 63;
    const int lrow = l & 15, lk = l >> 4;

    f32x4 acc[2][4];
    {
        // B fragments for W1 (global, L2-hot)
        bf16x8 bfr[4][2];
        #pragma unroll
        for (int cg = 0; cg < 4; ++cg)
            #pragma unroll
            for (int k2 = 0; k2 < 2; ++k2)
                bfr[cg][k2] = *reinterpret_cast<const bf16x8*>(
                    wt1 + (cg * 16 + lrow) * 64 + (lk + k2 * 4) * 8);
        #pragma unroll
        for (int er = 0; er < 2; ++er) {
            int r = row0 + wv * 32 + er * 16 + lrow;
            bf16x8 a0, a1;
            if (r < N) {
                const float4* ap = reinterpret_cast<const float4*>(A1 + (size_t)r * 64);
                a0 = cvt8(ap[lk * 2],       ap[lk * 2 + 1]);
                a1 = cvt8(ap[(lk + 4) * 2], ap[(lk + 4) * 2 + 1]);
            } else {
                a0 = bf16x8{0,0,0,0,0,0,0,0}; a1 = a0;
            }
            #pragma unroll
            for (int cg = 0; cg < 4; ++cg) {
                f32x4 zz = {0.f, 0.f, 0.f, 0.f};
                acc[er][cg] = __builtin_amdgcn_mfma_f32_16x16x32_bf16(a0, bfr[cg][0], zz, 0, 0, 0);
                acc[er][cg] = __builtin_amdgcn_mfma_f32_16x16x32_bf16(a1, bfr[cg][1], acc[er][cg], 0, 0, 0);
            }
        }
    }
    if (TWO) {
        bf16x8 bfr[4][2];
        #pragma unroll
        for (int cg = 0; cg < 4; ++cg)
            #pragma unroll
            for (int k2 = 0; k2 < 2; ++k2)
                bfr[cg][k2] = *reinterpret_cast<const bf16x8*>(
                    wt2 + (cg * 16 + lrow) * 64 + (lk + k2 * 4) * 8);
        #pragma unroll
        for (int er = 0; er < 2; ++er) {
            int r = row0 + wv * 32 + er * 16 + lrow;
            bf16x8 a0, a1;
            if (r < N) {
                const float4* ap = reinterpret_cast<const float4*>(A2 + (size_t)r * 64);
                a0 = cvt8(ap[lk * 2],       ap[lk * 2 + 1]);
                a1 = cvt8(ap[(lk + 4) * 2], ap[(lk + 4) * 2 + 1]);
            } else {
                a0 = bf16x8{0,0,0,0,0,0,0,0}; a1 = a0;
            }
            #pragma unroll
            for (int cg = 0; cg < 4; ++cg) {
                acc[er][cg] = __builtin_amdgcn_mfma_f32_16x16x32_bf16(a0, bfr[cg][0], acc[er][cg], 0, 0, 0);
                acc[er][cg] = __builtin_amdgcn_mfma_f32_16x16x32_bf16(a1, bfr[cg][1], acc[er][cg], 0, 0, 0);
            }
        }
    }

    // epilogue: C/D mapping col=lane&15, row=(lane>>4)*4+reg (verified)
    #pragma unroll
    for (int er = 0; er < 2; ++er) {
        int rbase = row0 + wv * 32 + er * 16 + (lk << 2);
        #pragma unroll
        for (int cg = 0; cg < 4; ++cg) {
            int col = cg * 16 + lrow;
            float bv = bias[col];
            #pragma unroll
            for (int j = 0; j < 4; ++j) {
                int r = rbase + j;
                if (r < N) {
                    float v = acc[er][cg][j] + bv;
                    if (TANH) v = fast_tanh(v);
                    outp[(size_t)r * 64 + col] = v;
                    if (ZEROP) pooled[(size_t)r * 64 + col] = 0.f;
                }
            }
        }
    }
}

// ---------------- MFMA fused edge kernel v2 (low-LDS, high-occupancy) ----------------
// Per chunk of 128 CSR slots: A fragments loaded DIRECTLY from global
// (layer1: ef fp32 -> bf16 in-reg, also persisting CSR-ordered efb;
//  layer2: efb bf16), W fragments direct from global (L2-hot 8 KB),
// MFMA -> epilogue gathers fp32 hm[src] + tanh -> bf16 LDS msg tile ->
// segment-sum (wave-per-node, lane=channel) into pooled.
__global__ void __launch_bounds__(256, 4) fused_edge_gather(
    const float* __restrict__ ef, unsigned short* __restrict__ efb,
    const float* __restrict__ hm,
    const int* __restrict__ src, const int* __restrict__ dst,
    const int* __restrict__ off, const int* __restrict__ eidx,
    const unsigned short* __restrict__ wtb, float* __restrict__ pooled,
    int E, int N, int layer1)
{
    __shared__ unsigned short ldsM[128 * 66];   // msg bf16, padded (16.9 KB)
    __shared__ int ldsE[128];
    __shared__ int ldsSrc[128];

    const int t  = threadIdx.x;
    const int s0 = blockIdx.x * 256;
    const int wv = t >> 6, l = t & 63;
    const int lrow = l & 15, lk = l >> 4;

    // B fragments from global (same 8 KB for all blocks -> L2 broadcast)
    bf16x8 bfr[4][2];
    #pragma unroll
    for (int cg = 0; cg < 4; ++cg)
        #pragma unroll
        for (int k2 = 0; k2 < 2; ++k2)
            bfr[cg][k2] = *reinterpret_cast<const bf16x8*>(
                wtb + (cg * 16 + lrow) * 64 + (lk + k2 * 4) * 8);

    #pragma unroll 1
    for (int ck = 0; ck < 2; ++ck) {
        int cb = s0 + ck * 128;
        // stage edge indices + src rows (tiny)
        if (t < 128) {
            int slot = cb + t;
            int e = (slot < E) ? eidx[slot] : 0;
            ldsE[t] = e;
            ldsSrc[t] = (slot < E) ? src[e] : 0;
        }
        __syncthreads();

        // A fragments direct from global (+ efb persist on layer 1)
        bf16x8 afr[2][2];
        #pragma unroll
        for (int er = 0; er < 2; ++er) {
            int row = wv * 32 + er * 16 + lrow;
            int slotr = cb + row;
            if (slotr < E) {
                if (layer1) {
                    int e = ldsE[row];
                    const float4* ap = reinterpret_cast<const float4*>(ef + (size_t)e * 64);
                    #pragma unroll
                    for (int k2 = 0; k2 < 2; ++k2) {
                        int cc = lk + k2 * 4;
                        bf16x8 v = cvt8(ap[cc * 2], ap[cc * 2 + 1]);
                        afr[er][k2] = v;
                        *reinterpret_cast<bf16x8*>(efb + (size_t)slotr * 64 + cc * 8) = v;
                    }
                } else {
                    #pragma unroll
                    for (int k2 = 0; k2 < 2; ++k2) {
                        int cc = lk + k2 * 4;
                        afr[er][k2] = *reinterpret_cast<const bf16x8*>(
                            efb + (size_t)slotr * 64 + cc * 8);
                    }
                }
            } else {
                bf16x8 z = {0,0,0,0,0,0,0,0};
                afr[er][0] = z; afr[er][1] = z;
            }
        }

        // MFMA [128x64] = A @ Wt
        f32x4 acc[2][4];
        #pragma unroll
        for (int er = 0; er < 2; ++er) {
            #pragma unroll
            for (int cg = 0; cg < 4; ++cg) {
                f32x4 zz = {0.f, 0.f, 0.f, 0.f};
                acc[er][cg] = __builtin_amdgcn_mfma_f32_16x16x32_bf16(
                    afr[er][0], bfr[cg][0], zz, 0, 0, 0);
                acc[er][cg] = __builtin_amdgcn_mfma_f32_16x16x32_bf16(
                    afr[er][1], bfr[cg][1], acc[er][cg], 0, 0, 0);
            }
        }

        // epilogue: + hm[src] (fp32 gather), tanh, -> bf16 LDS msg tile
        #pragma unroll
        for (int er = 0; er < 2; ++er) {
            int rb = wv * 32 + er * 16 + (lk << 2);
            int sA = ldsSrc[rb + 0], sB = ldsSrc[rb + 1];
            int sC = ldsSrc[rb + 2], sD = ldsSrc[rb + 3];
            #pragma unroll
            for (int cg = 0; cg < 4; ++cg) {
                int col = cg * 16 + lrow;
                float hA = hm[(size_t)sA * 64 + col];
                float hB = hm[(size_t)sB * 64 + col];
                float hC = hm[(size_t)sC * 64 + col];
                float hD = hm[(size_t)sD * 64 + col];
                ldsM[(rb + 0) * 66 + col] = (unsigned short)f2bf(fast_tanh(acc[er][cg][0] + hA));
                ldsM[(rb + 1) * 66 + col] = (unsigned short)f2bf(fast_tanh(acc[er][cg][1] + hB));
                ldsM[(rb + 2) * 66 + col] = (unsigned short)f2bf(fast_tanh(acc[er][cg][2] + hC));
                ldsM[(rb + 3) * 66 + col] = (unsigned short)f2bf(fast_tanh(acc[er][cg][3] + hD));
            }
        }
        __syncthreads();

        // phase 2: segment-sum from LDS; wave per node, lane = channel
        {
            int ce = cb + 128; if (ce > E) ce = E;
            if (cb < E) {
                int df = dst[ldsE[0]];
                int dl = dst[ldsE[ce - 1 - cb]];
                for (int n = df + wv; n <= dl; n += 4) {
                    int lo = off[n], hi = off[n + 1];
                    int clo = lo > cb ? lo : cb;
                    int chi = hi < ce ? hi : ce;
                    if (clo >= chi) continue;
                    float v = 0.f;
                    for (int q = clo; q < chi; ++q)
                        v += bf2f(ldsM[(q - cb) * 66 + l]);
                    if (lo >= cb && hi <= ce) pooled[(size_t)n * 64 + l] = v;
                    else atomicAdd(pooled + (size_t)n * 64 + l, v);
                }
            }
        }
        __syncthreads();   // before next chunk overwrites ldsE/ldsM
    }
}

// ---------------- scalar fallback kernels (ws too small; fp32 exact) ----------------

__global__ void __launch_bounds__(256, 2) node_transform(
    const float* __restrict__ h, const float* __restrict__ W,
    const float* __restrict__ b, float* __restrict__ hm,
    float* __restrict__ pooled, int N)
{
    int n = blockIdx.x * 256 + threadIdx.x;
    if (n >= N) return;
    float acc[DD];
    #pragma unroll
    for (int j = 0; j < DD; ++j) acc[j] = b[j];
    const float4* hrow = reinterpret_cast<const float4*>(h + (size_t)n * DD);
    #pragma unroll
    for (int kk = 0; kk < DD / 4; ++kk) {
        float4 a = hrow[kk];
        const float* Wr = W + kk * 4 * DD;
        #pragma unroll
        for (int j = 0; j < DD; ++j)
            acc[j] += a.x * Wr[j] + a.y * Wr[DD + j]
                    + a.z * Wr[2 * DD + j] + a.w * Wr[3 * DD + j];
    }
    float4* orow = reinterpret_cast<float4*>(hm + (size_t)n * DD);
    float4* prow = reinterpret_cast<float4*>(pooled + (size_t)n * DD);
    #pragma unroll
    for (int jj = 0; jj < DD / 4; ++jj) {
        orow[jj] = make_float4(acc[4*jj], acc[4*jj+1], acc[4*jj+2], acc[4*jj+3]);
        prow[jj] = make_float4(0.f, 0.f, 0.f, 0.f);
    }
}

__global__ void __launch_bounds__(256, 2) edge_kernel_atomic(
    const float* __restrict__ ef, const float* __restrict__ hm,
    const int* __restrict__ src, const int* __restrict__ dst,
    const float* __restrict__ W, float* __restrict__ pooled, int E)
{
    int e = blockIdx.x * 256 + threadIdx.x;
    if (e >= E) return;
    int s = src[e];
    int d = dst[e];
    float acc[DD];
    #pragma unroll
    for (int j = 0; j < DD; ++j) acc[j] = 0.0f;
    const float4* erow = reinterpret_cast<const float4*>(ef + (size_t)e * DD);
    #pragma unroll
    for (int kk = 0; kk < DD / 4; ++kk) {
        float4 a = erow[kk];
        const float* Wr = W + kk * 4 * DD;
        #pragma unroll
        for (int j = 0; j < DD; ++j)
            acc[j] += a.x * Wr[j] + a.y * Wr[DD + j]
                    + a.z * Wr[2 * DD + j] + a.w * Wr[3 * DD + j];
    }
    const float4* hrow = reinterpret_cast<const float4*>(hm + (size_t)s * DD);
    float* prow = pooled + (size_t)d * DD;
    #pragma unroll
    for (int jj = 0; jj < DD / 4; ++jj) {
        float4 hv = hrow[jj];
        atomicAdd(prow + 4*jj + 0, fast_tanh(acc[4*jj+0] + hv.x));
        atomicAdd(prow + 4*jj + 1, fast_tanh(acc[4*jj+1] + hv.y));
        atomicAdd(prow + 4*jj + 2, fast_tanh(acc[4*jj+2] + hv.z));
        atomicAdd(prow + 4*jj + 3, fast_tanh(acc[4*jj+3] + hv.w));
    }
}

__global__ void __launch_bounds__(256, 2) update_kernel(
    const float* __restrict__ h, const float* __restrict__ pooled,
    const float* __restrict__ Wu, const float* __restrict__ bu,
    float* __restrict__ hout, int N)
{
    int n = blockIdx.x * 256 + threadIdx.x;
    if (n >= N) return;
    float acc[DD];
    #pragma unroll
    for (int j = 0; j < DD; ++j) acc[j] = bu[j];
    const float4* hrow = reinterpret_cast<const float4*>(h + (size_t)n * DD);
    #pragma unroll
    for (int kk = 0; kk < DD / 4; ++kk) {
        float4 a = hrow[kk];
        const float* Wr = Wu + kk * 4 * DD;
        #pragma unroll
        for (int j = 0; j < DD; ++j)
            acc[j] += a.x * Wr[j] + a.y * Wr[DD + j]
                    + a.z * Wr[2 * DD + j] + a.w * Wr[3 * DD + j];
    }
    const float4* prow = reinterpret_cast<const float4*>(pooled + (size_t)n * DD);
    #pragma unroll
    for (int kk = 0; kk < DD / 4; ++kk) {
        float4 a = prow[kk];
        const float* Wr = Wu + (DD + kk * 4) * DD;
        #pragma unroll
        for (int j = 0; j < DD; ++j)
            acc[j] += a.x * Wr[j] + a.y * Wr[DD + j]
                    + a.z * Wr[2 * DD + j] + a.w * Wr[3 * DD + j];
    }
    float4* orow = reinterpret_cast<float4*>(hout + (size_t)n * DD);
    #pragma unroll
    for (int jj = 0; jj < DD / 4; ++jj)
        orow[jj] = make_float4(fast_tanh(acc[4*jj]),   fast_tanh(acc[4*jj+1]),
                               fast_tanh(acc[4*jj+2]), fast_tanh(acc[4*jj+3]));
}

__global__ void __launch_bounds__(256) out_kernel(
    const float* __restrict__ h, const float* __restrict__ Wo,
    const float* __restrict__ bo, float* __restrict__ out, int N)
{
    int n = blockIdx.x * 256 + threadIdx.x;
    if (n >= N) return;
    const float4* hrow = reinterpret_cast<const float4*>(h + (size_t)n * DD);
    float acc = bo[0];
    #pragma unroll
    for (int kk = 0; kk < DD / 4; ++kk) {
        float4 a = hrow[kk];
        acc += a.x * Wo[4*kk] + a.y * Wo[4*kk+1] + a.z * Wo[4*kk+2] + a.w * Wo[4*kk+3];
    }
    out[n] = acc;
}

extern "C" void kernel_launch(void* const* d_in, const int* in_sizes, int n_in,
                              void* d_out, int out_size, void* d_ws, size_t ws_size,
                              hipStream_t stream) {
    const float* node = (const float*)d_in[0];
    const float* ef   = (const float*)d_in[1];
    const int*   src  = (const int*)d_in[2];
    const int*   dst  = (const int*)d_in[3];
    const float* Wm1  = (const float*)d_in[4];
    const float* bm1  = (const float*)d_in[5];
    const float* Wu1  = (const float*)d_in[6];
    const float* bu1  = (const float*)d_in[7];
    const float* Wm2  = (const float*)d_in[8];
    const float* bm2  = (const float*)d_in[9];
    const float* Wu2  = (const float*)d_in[10];
    const float* bu2  = (const float*)d_in[11];
    const float* Wo   = (const float*)d_in[12];
    const float* bo   = (const float*)d_in[13];
    float* out = (float*)d_out;

    const int N = in_sizes[0] / DD;
    const int E = in_sizes[2];

    // ws layout
    char* p = (char*)d_ws;
    float* h1     = (float*)p; p += (size_t)N * DD * 4;
    float* h2     = (float*)p; p += (size_t)N * DD * 4;
    float* hm     = (float*)p; p += (size_t)N * DD * 4;
    float* pooled = (float*)p; p += (size_t)N * DD * 4;
    unsigned short* efb = (unsigned short*)p; p += (size_t)E * DD * 2;
    unsigned short* wt  = (unsigned short*)p; p += (size_t)8 * DD * DD * 2;
    int*   deg    = (int*)p;   p += (size_t)N * 4;
    int*   off    = (int*)p;   p += (size_t)(N + 1) * 4;
    int*   cursor = (int*)p;   p += (size_t)N * 4;
    int*   eidx   = (int*)p;   p += (size_t)E * 4;
    size_t needed = (size_t)(p - (char*)d_ws);

    dim3 blk(256);
    int nbN = (N + 255) / 256;
    int nbE = (E + 255) / 256;
    int nbT = (N + 127) / 128;

    if (ws_size >= needed) {
        // ---- CSR build + weight prep (stateless: rebuilt every call) ----
        hipMemsetAsync(deg, 0, (size_t)N * 4, stream);
        count_deg<<<nbE, blk, 0, stream>>>(dst, deg, E);
        scan_kernel<<<1, 1024, 0, stream>>>(deg, off, cursor, N);
        fill_eidx<<<nbE, blk, 0, stream>>>(dst, cursor, eidx, E);
        prep_wt_all<<<128, blk, 0, stream>>>(Wm1, Wu1, Wm2, Wu2, wt);

        // ---- layer 1 ----
        node_mfma<false, false, true><<<nbT, blk, 0, stream>>>(
            node, nullptr, wt + 0 * 4096, nullptr, bm1, hm, pooled, N);
        fused_edge_gather<<<nbE, blk, 0, stream>>>(ef, efb, hm, src, dst, off, eidx,
                                                   wt + 1 * 4096, pooled, E, N, 1);
        node_mfma<true, true, false><<<nbT, blk, 0, stream>>>(
            node, pooled, wt + 2 * 4096, wt + 3 * 4096, bu1, h1, nullptr, N);

        // ---- layer 2 ----
        node_mfma<false, false, true><<<nbT, blk, 0, stream>>>(
            h1, nullptr, wt + 4 * 4096, nullptr, bm2, hm, pooled, N);
        fused_edge_gather<<<nbE, blk, 0, stream>>>(ef, efb, hm, src, dst, off, eidx,
                                                   wt + 5 * 4096, pooled, E, N, 0);
        node_mfma<true, true, false><<<nbT, blk, 0, stream>>>(
            h1, pooled, wt + 6 * 4096, wt + 7 * 4096, bu2, h2, nullptr, N);
    } else {
        // ---- fallback: atomic scatter path (fp32 exact) ----
        node_transform<<<nbN, blk, 0, stream>>>(node, Wm1, bm1, hm, pooled, N);
        edge_kernel_atomic<<<nbE, blk, 0, stream>>>(ef, hm, src, dst, Wm1 + DD * DD, pooled, E);
        update_kernel<<<nbN, blk, 0, stream>>>(node, pooled, Wu1, bu1, h1, N);

        node_transform<<<nbN, blk, 0, stream>>>(h1, Wm2, bm2, hm, pooled, N);
        edge_kernel_atomic<<<nbE, blk, 0, stream>>>(ef, hm, src, dst, Wm2 + DD * DD, pooled, E);
        update_kernel<<<nbN, blk, 0, stream>>>(h1, pooled, Wu2, bu2, h2, N);
    }

    // ---- readout ----
    out_kernel<<<nbN, blk, 0, stream>>>(h2, Wo, bo, out, N);
}